// Round 1
// baseline (279.846 us; speedup 1.0000x reference)
//
#include <hip/hip_runtime.h>
#include <hip/hip_bf16.h>
#include <math.h>

#define DD 768
#define BB 32
#define PP 512
#define TT 512
#define CC 97
#define THRESH 0.8f

typedef __attribute__((ext_vector_type(8))) short short8;
typedef __attribute__((ext_vector_type(4))) float f32x4;

// ---------------- stage 1a: normalize entity pairs -> bf16 unit vecs ----------
__global__ void norm_pairs_kernel(const float* __restrict__ pairs,
                                  __hip_bfloat16* __restrict__ ph,
                                  __hip_bfloat16* __restrict__ pt) {
    int row = blockIdx.x;            // B*P rows
    int tid = threadIdx.x;           // 256 threads
    const float* src = pairs + (size_t)row * (2 * DD);

    float xh[3], xt[3];
    float sh = 0.f, st = 0.f;
#pragma unroll
    for (int j = 0; j < 3; ++j) {
        xh[j] = src[j * 256 + tid];
        xt[j] = src[DD + j * 256 + tid];
        sh += xh[j] * xh[j];
        st += xt[j] * xt[j];
    }
    // wave reduce (width 64)
    for (int off = 32; off; off >>= 1) {
        sh += __shfl_down(sh, off);
        st += __shfl_down(st, off);
    }
    __shared__ float red[2][5];
    int wid = tid >> 6, lane = tid & 63;
    if (lane == 0) { red[0][wid] = sh; red[1][wid] = st; }
    __syncthreads();
    if (tid == 0) {
        float a = red[0][0] + red[0][1] + red[0][2] + red[0][3];
        float b = red[1][0] + red[1][1] + red[1][2] + red[1][3];
        red[0][4] = 1.0f / fmaxf(sqrtf(a), 1e-8f);
        red[1][4] = 1.0f / fmaxf(sqrtf(b), 1e-8f);
    }
    __syncthreads();
    float ih = red[0][4], it = red[1][4];
    __hip_bfloat16* dh = ph + (size_t)row * DD;
    __hip_bfloat16* dt = pt + (size_t)row * DD;
#pragma unroll
    for (int j = 0; j < 3; ++j) {
        dh[j * 256 + tid] = __float2bfloat16(xh[j] * ih);
        dt[j * 256 + tid] = __float2bfloat16(xt[j] * it);
    }
}

// ---------------- stage 1b: normalize triplets -> bf16 unit vecs + rel ids ----
__global__ void norm_trip_kernel(const float* __restrict__ trip,
                                 __hip_bfloat16* __restrict__ gh,
                                 __hip_bfloat16* __restrict__ gt,
                                 int* __restrict__ rel) {
    int row = blockIdx.x;            // B*T rows
    int tid = threadIdx.x;
    const float* src = trip + (size_t)row * (2 * DD + 1);

    float xh[3], xt[3];
    float sh = 0.f, st = 0.f;
#pragma unroll
    for (int j = 0; j < 3; ++j) {
        xh[j] = src[j * 256 + tid];
        xt[j] = src[DD + 1 + j * 256 + tid];
        sh += xh[j] * xh[j];
        st += xt[j] * xt[j];
    }
    for (int off = 32; off; off >>= 1) {
        sh += __shfl_down(sh, off);
        st += __shfl_down(st, off);
    }
    __shared__ float red[2][5];
    int wid = tid >> 6, lane = tid & 63;
    if (lane == 0) { red[0][wid] = sh; red[1][wid] = st; }
    __syncthreads();
    if (tid == 0) {
        float a = red[0][0] + red[0][1] + red[0][2] + red[0][3];
        float b = red[1][0] + red[1][1] + red[1][2] + red[1][3];
        red[0][4] = 1.0f / fmaxf(sqrtf(a), 1e-8f);
        red[1][4] = 1.0f / fmaxf(sqrtf(b), 1e-8f);
        rel[row] = (int)src[DD];
    }
    __syncthreads();
    float ih = red[0][4], it = red[1][4];
    __hip_bfloat16* dh = gh + (size_t)row * DD;
    __hip_bfloat16* dt = gt + (size_t)row * DD;
#pragma unroll
    for (int j = 0; j < 3; ++j) {
        dh[j * 256 + tid] = __float2bfloat16(xh[j] * ih);
        dt[j * 256 + tid] = __float2bfloat16(xt[j] * it);
    }
}

// ---------------- stage 2: all-pairs sims via MFMA + thresholded argmax -------
// grid: (P/16, B).  block: 256 = 4 waves.  Each wave covers t-range [w*128,(w+1)*128).
__global__ __launch_bounds__(256) void match_kernel(
        const __hip_bfloat16* __restrict__ ph, const __hip_bfloat16* __restrict__ pt,
        const __hip_bfloat16* __restrict__ gh, const __hip_bfloat16* __restrict__ gt,
        const int* __restrict__ rel, int* __restrict__ tgt) {
    int b = blockIdx.y;
    int ptile = blockIdx.x;                  // 16 pred rows per block
    int tid = threadIdx.x;
    int w = tid >> 6, l = tid & 63;
    int l15 = l & 15, lg = l >> 4;           // 16-lane group id 0..3

    const __hip_bfloat16* phb = ph + ((size_t)(b * PP + ptile * 16)) * DD;
    const __hip_bfloat16* ptb = pt + ((size_t)(b * PP + ptile * 16)) * DD;
    const __hip_bfloat16* ghb = gh + (size_t)b * TT * DD;
    const __hip_bfloat16* gtb = gt + (size_t)b * TT * DD;

    float bestv[4];
    int bestt[4];
#pragma unroll
    for (int r = 0; r < 4; ++r) { bestv[r] = -INFINITY; bestt[r] = 0; }

    // per wave: 2 t-tiles of 64 cols each
    for (int q = 0; q < 2; ++q) {
        int t0 = (w * 2 + q) * 64;
        f32x4 accH[4], accT[4];
#pragma unroll
        for (int n = 0; n < 4; ++n) {
            accH[n] = (f32x4){0.f, 0.f, 0.f, 0.f};
            accT[n] = (f32x4){0.f, 0.f, 0.f, 0.f};
        }
        for (int k0 = 0; k0 < DD; k0 += 32) {
            int ka = k0 + lg * 8;            // this lane's 8 contiguous k's
            short8 a_h = *(const short8*)(phb + (size_t)l15 * DD + ka);
            short8 a_t = *(const short8*)(ptb + (size_t)l15 * DD + ka);
#pragma unroll
            for (int n = 0; n < 4; ++n) {
                int trow = t0 + n * 16 + l15;
                short8 b_h = *(const short8*)(ghb + (size_t)trow * DD + ka);
                accH[n] = __builtin_amdgcn_mfma_f32_16x16x32_bf16(a_h, b_h, accH[n], 0, 0, 0);
                short8 b_t = *(const short8*)(gtb + (size_t)trow * DD + ka);
                accT[n] = __builtin_amdgcn_mfma_f32_16x16x32_bf16(a_t, b_t, accT[n], 0, 0, 0);
            }
        }
        // threshold + scored + running argmax (t increases with q,n -> strict > keeps first)
#pragma unroll
        for (int n = 0; n < 4; ++n) {
#pragma unroll
            for (int r = 0; r < 4; ++r) {
                float h = accH[n][r], tl = accT[n][r];
                bool ok = (h > THRESH) && (tl > THRESH);
                float sc = ok ? 0.5f * (h + tl) : -INFINITY;
                int t = t0 + n * 16 + l15;
                if (sc > bestv[r]) { bestv[r] = sc; bestt[r] = t; }
            }
        }
    }

    // cross-lane reduce within each 16-lane group (cols of the C tile)
#pragma unroll
    for (int r = 0; r < 4; ++r) {
        float v = bestv[r]; int t = bestt[r];
        for (int m = 1; m < 16; m <<= 1) {
            float v2 = __shfl_xor(v, m);
            int t2 = __shfl_xor(t, m);
            if (v2 > v || (v2 == v && t2 < t)) { v = v2; t = t2; }
        }
        bestv[r] = v; bestt[r] = t;
    }

    // merge the 4 waves (disjoint t-ranges) via LDS
    __shared__ float sv[4][16];
    __shared__ int stt[4][16];
    if (l15 == 0) {
#pragma unroll
        for (int r = 0; r < 4; ++r) {
            sv[w][lg * 4 + r] = bestv[r];
            stt[w][lg * 4 + r] = bestt[r];
        }
    }
    __syncthreads();
    if (tid < 16) {
        float v = sv[0][tid]; int t = stt[0][tid];
#pragma unroll
        for (int ww = 1; ww < 4; ++ww) {
            float v2 = sv[ww][tid]; int t2 = stt[ww][tid];
            if (v2 > v || (v2 == v && t2 < t)) { v = v2; t = t2; }
        }
        int target = (v > -INFINITY) ? rel[b * TT + t] : 0;
        tgt[b * PP + ptile * 16 + tid] = target;
    }
}

// ---------------- stage 3: per-row NLL from log-softmax ----------------------
// block = 256 = 4 waves, one row per wave. partials[block] = sum of 4 nll values.
__global__ void nll_kernel(const float* __restrict__ preds,
                           const int* __restrict__ tgt,
                           float* __restrict__ partials) {
    int w = threadIdx.x >> 6, l = threadIdx.x & 63;
    int row = blockIdx.x * 4 + w;
    const float* x = preds + (size_t)row * CC;

    float a = x[l];
    float b2 = (l + 64 < CC) ? x[l + 64] : -INFINITY;
    float mx = fmaxf(a, b2);
    for (int m = 32; m; m >>= 1) mx = fmaxf(mx, __shfl_xor(mx, m));
    float e = __expf(a - mx) + ((l + 64 < CC) ? __expf(b2 - mx) : 0.0f);
    for (int m = 32; m; m >>= 1) e += __shfl_xor(e, m);

    __shared__ float part[4];
    if (l == 0) {
        int tg = tgt[row];
        part[w] = mx + logf(e) - x[tg];
    }
    __syncthreads();
    if (threadIdx.x == 0)
        partials[blockIdx.x] = part[0] + part[1] + part[2] + part[3];
}

// ---------------- stage 4: final mean ----------------------------------------
__global__ void final_reduce_kernel(const float* __restrict__ partials, int n,
                                    float* __restrict__ out) {
    float s = 0.f;
    for (int i = threadIdx.x; i < n; i += 256) s += partials[i];
    for (int m = 32; m; m >>= 1) s += __shfl_xor(s, m);
    __shared__ float ps[4];
    if ((threadIdx.x & 63) == 0) ps[threadIdx.x >> 6] = s;
    __syncthreads();
    if (threadIdx.x == 0)
        out[0] = (ps[0] + ps[1] + ps[2] + ps[3]) / (float)(BB * PP);
}

extern "C" void kernel_launch(void* const* d_in, const int* in_sizes, int n_in,
                              void* d_out, int out_size, void* d_ws, size_t ws_size,
                              hipStream_t stream) {
    const float* pairs = (const float*)d_in[0];  // [B,P,1536]
    const float* preds = (const float*)d_in[1];  // [B,P,97]
    const float* trip  = (const float*)d_in[2];  // [B,T,1537]
    float* out = (float*)d_out;

    char* ws = (char*)d_ws;
    size_t vec_bytes = (size_t)BB * PP * DD * sizeof(__hip_bfloat16);  // 25,165,824
    __hip_bfloat16* ph = (__hip_bfloat16*)(ws);
    __hip_bfloat16* pt = (__hip_bfloat16*)(ws + vec_bytes);
    __hip_bfloat16* gh = (__hip_bfloat16*)(ws + 2 * vec_bytes);
    __hip_bfloat16* gt = (__hip_bfloat16*)(ws + 3 * vec_bytes);
    int* rel  = (int*)(ws + 4 * vec_bytes);
    int* tgt  = (int*)(ws + 4 * vec_bytes + (size_t)BB * TT * sizeof(int));
    float* partials = (float*)(ws + 4 * vec_bytes + (size_t)BB * TT * sizeof(int)
                               + (size_t)BB * PP * sizeof(int));

    norm_pairs_kernel<<<BB * PP, 256, 0, stream>>>(pairs, ph, pt);
    norm_trip_kernel<<<BB * TT, 256, 0, stream>>>(trip, gh, gt, rel);
    match_kernel<<<dim3(PP / 16, BB), 256, 0, stream>>>(ph, pt, gh, gt, rel, tgt);
    nll_kernel<<<BB * PP / 4, 256, 0, stream>>>(preds, tgt, partials);
    final_reduce_kernel<<<1, 256, 0, stream>>>(partials, BB * PP / 4, out);
}